// Round 1
// baseline (1091.854 us; speedup 1.0000x reference)
//
#include <hip/hip_runtime.h>
#include <stdint.h>

// SoftKMeans fused: dist = cdist(x, centroids), soft = softmax(-dist), loss = sum(soft*sq)/B
// x: (16,8192,256) fp32  -> M = 131072 rows, D = 256
// centroids: (1024,256) fp32 -> K = 1024 cols
// out: soft (131072*1024 fp32) ++ loss (1 fp32)
//
// R1: occupancy restructure. Previous version held 64 rows x 1024 cols per
// 512-thread block -> 128 acc VGPRs/lane -> ~228 unified regs -> 2 waves/SIMD
// (23% occupancy, ONE block/CU) -> K-loop L2/HBM latency and the epilogue
// serialize with nothing to hide behind. Now: 16 rows x 1024 cols per
// 256-thread block (4 waves = 4 col-groups of 256), acc = 64 regs/lane,
// __launch_bounds__(256,4) -> target 16 waves / 4 independent blocks per CU so
// one block's memory-phase overlaps another's VALU/store-phase.
// Centroids pre-converted to bf16 in ws (512KB, L2-resident), x2/c2 kept fp32
// so only the cross term carries bf16 error.

typedef float  f32x4  __attribute__((ext_vector_type(4)));
typedef short  s16x8  __attribute__((ext_vector_type(8)));
typedef unsigned int u32x4 __attribute__((ext_vector_type(4)));
typedef unsigned int u32x2 __attribute__((ext_vector_type(2)));

#define DD 256
#define KC 1024
#define MTOT 131072
#define ROWS 16
#define LOSS_IDX ((size_t)MTOT * (size_t)KC)

__device__ __forceinline__ unsigned short bf16_rne(float f) {
  unsigned int u = __builtin_bit_cast(unsigned int, f);
  u += 0x7fffu + ((u >> 16) & 1u);   // round-to-nearest-even (no NaNs in data)
  return (unsigned short)(u >> 16);
}

// prep: centroids fp32 -> bf16 into ws, c2 = ||c||^2 fp32, zero the loss slot.
__global__ void skm_prep(const float* __restrict__ cent,
                         unsigned short* __restrict__ cbf,
                         float* __restrict__ c2,
                         float* __restrict__ out) {
  const int c = blockIdx.x;       // 1024 blocks, one centroid each
  const int t = threadIdx.x;      // 64 threads: 4 floats each
  const float* p = cent + (size_t)c * DD + t * 4;
  float v0 = p[0], v1 = p[1], v2 = p[2], v3 = p[3];
  u32x2 pack;
  pack.x = (unsigned int)bf16_rne(v0) | ((unsigned int)bf16_rne(v1) << 16);
  pack.y = (unsigned int)bf16_rne(v2) | ((unsigned int)bf16_rne(v3) << 16);
  *(u32x2*)(cbf + (size_t)c * DD + t * 4) = pack;
  float s = v0*v0 + v1*v1 + v2*v2 + v3*v3;
  #pragma unroll
  for (int off = 32; off >= 1; off >>= 1) s += __shfl_xor(s, off, 64);
  if (t == 0) c2[c] = s;
  if (c == 0 && t == 0) out[LOSS_IDX] = 0.0f;   // harness poisons d_out each call
}

__global__ __launch_bounds__(256, 4) void skm_main(
    const float* __restrict__ x,
    const unsigned short* __restrict__ cbf,
    const float* __restrict__ c2,
    float* __restrict__ out) {
  __shared__ float s_x2[ROWS];
  __shared__ float s_r1[ROWS][4];
  __shared__ float s_r2[ROWS][4];
  __shared__ float s_row[ROWS];

  const int tid  = threadIdx.x;
  const int wave = tid >> 6;       // = col group, 0..3
  const int lane = tid & 63;
  const int quad = lane >> 4;      // 0..3
  const int l16  = lane & 15;      // 0..15
  const int rowbase = blockIdx.x * ROWS;
  const int colbase = wave * 256;

  // acc[tc]: row = quad*4 + rr, col = colbase + tc*16 + l16
  f32x4 acc[16];
  #pragma unroll
  for (int tc = 0; tc < 16; ++tc)
    acc[tc] = (f32x4){0.f, 0.f, 0.f, 0.f};

  float x2p = 0.f;

  // A-frag layout (verified): A[m = lane&15][k = quad*8 + j], j contiguous.
  const float* pa0 = x + (size_t)(rowbase + l16) * DD + quad * 8;
  // B-frag: lane holds cent[col = colbase + tc*16 + l16][k = quad*8 + j] (contiguous bf16 -> 16B load)
  const unsigned short* pb0 = cbf + (size_t)(colbase + l16) * DD + quad * 8;

  #pragma unroll 2
  for (int kk = 0; kk < 8; ++kk) {     // D reduction, 32 per step
    const int ko = kk * 32;
    s16x8 afr;
    {
      f32x4 a0 = *(const f32x4*)(pa0 + ko);
      f32x4 a1 = *(const f32x4*)(pa0 + ko + 4);
      x2p += a0[0]*a0[0] + a0[1]*a0[1] + a0[2]*a0[2] + a0[3]*a0[3]
           + a1[0]*a1[0] + a1[1]*a1[1] + a1[2]*a1[2] + a1[3]*a1[3];
      afr[0] = (short)bf16_rne(a0[0]); afr[1] = (short)bf16_rne(a0[1]);
      afr[2] = (short)bf16_rne(a0[2]); afr[3] = (short)bf16_rne(a0[3]);
      afr[4] = (short)bf16_rne(a1[0]); afr[5] = (short)bf16_rne(a1[1]);
      afr[6] = (short)bf16_rne(a1[2]); afr[7] = (short)bf16_rne(a1[3]);
    }
    #pragma unroll
    for (int tc = 0; tc < 16; ++tc) {
      u32x4 braw = *(const u32x4*)(pb0 + (size_t)tc * 16 * DD + ko);
      s16x8 bfr = __builtin_bit_cast(s16x8, braw);
      acc[tc] = __builtin_amdgcn_mfma_f32_16x16x32_bf16(afr, bfr, acc[tc], 0, 0, 0);
    }
  }

  // x2: lane has partial for row l16 over k = quad*8+j (+32Z); reduce across quads.
  // All 4 waves computed identical values; wave 0 publishes.
  x2p += __shfl_xor(x2p, 16, 64); x2p += __shfl_xor(x2p, 32, 64);
  if (wave == 0 && quad == 0) s_x2[l16] = x2p;
  __syncthreads();

  const int r0 = quad * 4;             // row-in-wg for rr=0
  float x2r[4];
  #pragma unroll
  for (int rr = 0; rr < 4; ++rr) x2r[rr] = s_x2[r0 + rr];

  // sq -> dist (overwrite acc), track per-row min dist over this wave's cols
  float mn[4];
  #pragma unroll
  for (int rr = 0; rr < 4; ++rr) mn[rr] = 3.4e38f;

  #pragma unroll
  for (int tc = 0; tc < 16; ++tc) {
    float c2v = c2[colbase + tc * 16 + l16];
    f32x4 a = acc[tc];
    #pragma unroll
    for (int rr = 0; rr < 4; ++rr) {
      float s = x2r[rr] + c2v - 2.0f * a[rr];
      s = fmaxf(s, 0.0f);
      float d = sqrtf(s);
      a[rr] = d;
      mn[rr] = fminf(mn[rr], d);
    }
    acc[tc] = a;
  }

  // reduce min across the 16 lanes of each quad (cols), then across col groups via LDS
  #pragma unroll
  for (int rr = 0; rr < 4; ++rr)
    #pragma unroll
    for (int off = 1; off <= 8; off <<= 1)
      mn[rr] = fminf(mn[rr], __shfl_xor(mn[rr], off, 64));
  if (l16 == 0) {
    #pragma unroll
    for (int rr = 0; rr < 4; ++rr) s_r1[r0 + rr][wave] = mn[rr];
  }
  __syncthreads();
  if (tid < ROWS)
    s_row[tid] = fminf(fminf(s_r1[tid][0], s_r1[tid][1]), fminf(s_r1[tid][2], s_r1[tid][3]));
  __syncthreads();

  float dmn[4];
  #pragma unroll
  for (int rr = 0; rr < 4; ++rr) dmn[rr] = s_row[r0 + rr];

  // exp pass: e = exp(dmin - d) (max-subtracted logits), partial denom + loss numerator
  float sme[4], lse[4];
  #pragma unroll
  for (int rr = 0; rr < 4; ++rr) { sme[rr] = 0.f; lse[rr] = 0.f; }

  #pragma unroll
  for (int tc = 0; tc < 16; ++tc) {
    f32x4 a = acc[tc];
    #pragma unroll
    for (int rr = 0; rr < 4; ++rr) {
      float d = a[rr];
      float e = __expf(dmn[rr] - d);
      lse[rr] += e * d * d;            // soft*sq numerator (sq = d^2)
      sme[rr] += e;
      a[rr] = e;
    }
    acc[tc] = a;
  }

  #pragma unroll
  for (int rr = 0; rr < 4; ++rr)
    #pragma unroll
    for (int off = 1; off <= 8; off <<= 1) {
      sme[rr] += __shfl_xor(sme[rr], off, 64);
      lse[rr] += __shfl_xor(lse[rr], off, 64);
    }
  if (l16 == 0) {
    #pragma unroll
    for (int rr = 0; rr < 4; ++rr) {
      s_r1[r0 + rr][wave] = sme[rr];
      s_r2[r0 + rr][wave] = lse[rr];
    }
  }
  __syncthreads();
  if (wave == 0) {                     // whole wave 0 active -> shuffles well-defined
    const int rw = tid & 15;
    float den = s_r1[rw][0] + s_r1[rw][1] + s_r1[rw][2] + s_r1[rw][3];
    float num = s_r2[rw][0] + s_r2[rw][1] + s_r2[rw][2] + s_r2[rw][3];
    float r = 1.0f / den;
    if (tid < ROWS) s_row[tid] = r;
    float lv = (tid < ROWS) ? num * r : 0.0f;   // per-row sum(soft*sq)
    #pragma unroll
    for (int off = 1; off <= 32; off <<= 1) lv += __shfl_xor(lv, off, 64);
    if (tid == 0) atomicAdd(out + LOSS_IDX, lv * (1.0f / 16.0f));
  }
  __syncthreads();

  float rdv[4];
  #pragma unroll
  for (int rr = 0; rr < 4; ++rr) rdv[rr] = s_row[r0 + rr];

  // store soft = e * (1/den); 16 lanes of a quad write 64B contiguous per (rr,tc)
  #pragma unroll
  for (int rr = 0; rr < 4; ++rr) {
    size_t base = ((size_t)(rowbase + r0 + rr)) * KC + colbase + l16;
    float r = rdv[rr];
    #pragma unroll
    for (int tc = 0; tc < 16; ++tc)
      out[base + tc * 16] = acc[tc][rr] * r;
  }
}

extern "C" void kernel_launch(void* const* d_in, const int* in_sizes, int n_in,
                              void* d_out, int out_size, void* d_ws, size_t ws_size,
                              hipStream_t stream) {
  const float* x    = (const float*)d_in[0];
  const float* cent = (const float*)d_in[1];
  float* out = (float*)d_out;
  // ws layout: bf16 centroids (1024*256*2 = 512KB) | c2 (1024 fp32)
  unsigned short* cbf = (unsigned short*)d_ws;
  float* c2 = (float*)((char*)d_ws + (size_t)KC * DD * sizeof(unsigned short));

  skm_prep<<<KC, 64, 0, stream>>>(cent, cbf, c2, out);
  skm_main<<<MTOT / ROWS, 256, 0, stream>>>(x, cbf, c2, out);
}